// Round 4
// baseline (630.590 us; speedup 1.0000x reference)
//
#include <hip/hip_runtime.h>
#include <hip/hip_bf16.h>

// Problem geometry (from reference):
//   vision_x:            [B=4, T_VIS=32, D=4096] f32   d_in[0]
//   weight:              [VOCAB=32000, D=4096]  f32    d_in[1]
//   figure_token_weight: [2, D=4096]            f32    d_in[2]
//   text_input:          [B=4, T=2048]          int    d_in[3]
//   out:                 [B, T, D]              f32
//
// Semantics: out[b,t,:] = table[text_input[b,t]] where table is the per-batch
// concat [weight; figure_token_weight; vision_x[b]]  (V' = 32000+2+32 = 32034).
//
// Pure gather: ~134 MB read + ~134 MB write -> HBM-bound, roofline ~43 us.

#define VOCAB   32000
#define D       4096
#define D4      (D / 4)       // 1024 16-byte vectors per row
#define T_VIS   32
#define TOK_T   2048          // tokens per batch
#define NTOK    (4 * TOK_T)   // 8192 total tokens

// Native clang vector type — required by __builtin_nontemporal_store
// (HIP's float4 is a HIP_vector_type class and is rejected).
typedef float f32x4 __attribute__((ext_vector_type(4)));

__global__ __launch_bounds__(256) void embed_gather_kernel(
    const f32x4* __restrict__ vision,   // [B, T_VIS, D]
    const f32x4* __restrict__ weight,   // [VOCAB, D]
    const f32x4* __restrict__ fig,      // [2, D]
    const int*   __restrict__ idx,      // [B, T]
    f32x4*       __restrict__ out)      // [B, T, D]
{
    const int token = blockIdx.x;        // 0 .. NTOK-1
    const int b     = token >> 11;       // token / TOK_T (TOK_T = 2048)
    const int id    = idx[token];        // block-uniform -> scalar load

    const f32x4* src;
    if (id < VOCAB) {
        src = weight + (size_t)id * D4;
    } else if (id < VOCAB + 2) {
        src = fig + (size_t)(id - VOCAB) * D4;
    } else {
        src = vision + ((size_t)b * T_VIS + (size_t)(id - VOCAB - 2)) * D4;
    }

    f32x4* dst = out + (size_t)token * D4;

    // 256 threads x 4 iters x 16 B = 16 KB row copy, fully coalesced.
    // Normal loads (duplicate rows can hit L2/L3); non-temporal stores
    // (output is write-once, keep it from evicting table rows).
    #pragma unroll
    for (int i = 0; i < D4; i += 256) {
        f32x4 v = src[i + threadIdx.x];
        __builtin_nontemporal_store(v, &dst[i + threadIdx.x]);
    }
}

extern "C" void kernel_launch(void* const* d_in, const int* in_sizes, int n_in,
                              void* d_out, int out_size, void* d_ws, size_t ws_size,
                              hipStream_t stream) {
    const f32x4* vision = (const f32x4*)d_in[0];
    const f32x4* weight = (const f32x4*)d_in[1];
    const f32x4* fig    = (const f32x4*)d_in[2];
    const int*   idx    = (const int*)d_in[3];
    f32x4*       out    = (f32x4*)d_out;

    embed_gather_kernel<<<NTOK, 256, 0, stream>>>(vision, weight, fig, idx, out);
}